// Round 13
// baseline (608.445 us; speedup 1.0000x reference)
//
#include <hip/hip_runtime.h>
#include <hip/hip_bf16.h>
#include <math.h>

#define HD 1024
#define BD 32
#define TD 64
#define VD 32000
#define NWG 128   // recurrence blocks
#define GW  512   // persistent GEMM worker blocks (queue-fed)
#define NTM 16    // 2048/128 M-tiles (t-major)
#define NTN 250   // 32000/128 N-tiles
#define NTT (NTM * NTN)

typedef __attribute__((ext_vector_type(8))) short bf16x8;
typedef __attribute__((ext_vector_type(4))) float f32x4;

__device__ __forceinline__ short f2bf(float x) {
    __hip_bfloat16 h = __float2bfloat16(x);
    union { __hip_bfloat16 h; short s; } u; u.h = h; return u.s;
}
__device__ __forceinline__ float fsigmoid(float x) {
    return 1.f / (1.f + __expf(-x));
}
__device__ __forceinline__ float ftanh(float x) {
    return 1.f - 2.f / (__expf(2.f * x) + 1.f);
}

// h ping-pong buffers live in MFMA-A-fragment order (same for all WGs):
// element (b, j): kq=j>>8, ks=(j>>5)&7, hi=(j>>3)&3, e=j&7, f=b>>4, lo=b&15
// 16B unit u = ((kq*8+ks)*2+f)*64 + hi*16 + lo ; short addr = u*8 + e.

// ---------------- init: casts + bias fold + state init (proven R7-R10) ----------------
__global__ __launch_bounds__(256) void init_kernel(
    const float* __restrict__ Whh_f, const float* __restrict__ bih,
    const float* __restrict__ bhh,  const float* __restrict__ Wout_f,
    const float* __restrict__ h0,
    short* __restrict__ Whh_b, short* __restrict__ Wout_b,
    float* __restrict__ bias,  short* __restrict__ hb, int* __restrict__ ctr,
    float* __restrict__ rowsum)
{
    long i0 = (long)blockIdx.x * blockDim.x + threadIdx.x;
    long stride = (long)gridDim.x * blockDim.x;
    for (long i = i0; i < 256; i += stride) ctr[i] = 0;
    for (long i = i0; i < BD * TD; i += stride) rowsum[i] = 0.f;
    for (long i = i0; i < (long)VD * HD / 4; i += stride) {
        float4 x = ((const float4*)Wout_f)[i];
        short4 y; y.x = f2bf(x.x); y.y = f2bf(x.y); y.z = f2bf(x.z); y.w = f2bf(x.w);
        ((short4*)Wout_b)[i] = y;
    }
    for (long i = i0; i < (long)4 * HD * HD / 4; i += stride) {
        float4 x = ((const float4*)Whh_f)[i];
        short4 y; y.x = f2bf(x.x); y.y = f2bf(x.y); y.z = f2bf(x.z); y.w = f2bf(x.w);
        ((short4*)Whh_b)[i] = y;
    }
    for (long i = i0; i < 4 * HD; i += stride) bias[i] = bih[i] + bhh[i];
    for (long i = i0; i < BD * HD; i += stride) {   // ping buffer 0, fragment layout
        int b = (int)(i >> 10), j = (int)(i & 1023);
        int kq = j >> 8, ks = (j >> 5) & 7, hi = (j >> 3) & 3, e = j & 7;
        int u = ((kq * 8 + ks) * 2 + (b >> 4)) * 64 + hi * 16 + (b & 15);
        hb[u * 8 + e] = f2bf(h0[i]);
    }
}

// ---------------- fused: persistent LSTM (blocks 0..127) ---------------------
// ---------------- + queue-fed streaming logits GEMM (blocks 128..639) --------
// Sync via monotonic per-WG flags: producer WG w posts flags[w]=t+1 (one sc1
// store after the barrier drain); rec wave kq polls its quarter's 32 flags
// with one 32-lane load + __all; workers poll all 128 for tile readiness.
// No inter-worker barriers: deadlock-free under any dispatch order.
__global__ __launch_bounds__(256, 2) void fused_lstm_gemm(
    const short* __restrict__ Whh_b,   // [4096][1024] bf16
    const float* __restrict__ bias,    // [4096]
    const float* __restrict__ c0,      // [32][1024] f32
    short* __restrict__ hb,            // [2][4096 units] bf16 fragment layout
    short* __restrict__ Hmat,          // [64*32][1024] bf16, t-major
    const short* __restrict__ Bw,      // W_out [32000][1024] bf16
    const float* __restrict__ bout,    // [32000]
    float* __restrict__ C,             // [2048][32000] b-major rows
    float* __restrict__ rowsum,        // [2048] sum(exp) per output row
    int* __restrict__ flags,           // [128] per-WG completed-step count
    int* __restrict__ queue)           // [1] gemm tile queue
{
    __shared__ alignas(16) short lds[2 * 1024 * 8];   // 32 KiB worker ring
    __shared__ float rowsum_sh[128];
    __shared__ int tau_sh;
    const int tid = threadIdx.x;

    if (blockIdx.x < NWG) {
        // ================= recurrence role =================
        __builtin_amdgcn_s_setprio(2);          // rec is the critical path
        float (*gl)[32][36] = (float (*)[32][36])lds;
        const int w = blockIdx.x;
        const int kq = tid >> 6;
        const int l = tid & 63;
        const int lo = l & 15, hi = l >> 4;
        const int j0 = w * 8;
        const int kbase = kq * 256 + hi * 8;

        const short* wB0 = Whh_b + (long)((lo >> 3) * HD + j0 + (lo & 7)) * HD + kbase;
        const short* wB1 = Whh_b + (long)(((16 + lo) >> 3) * HD + j0 + ((16 + lo) & 7)) * HD + kbase;
        bf16x8 wb0[8], wb1[8];
        #pragma unroll
        for (int ks = 0; ks < 8; ks++) {
            wb0[ks] = *(const bf16x8*)(wB0 + ks * 32);
            wb1[ks] = *(const bf16x8*)(wB1 + ks * 32);
        }

        const int cb = tid >> 3, cjl = tid & 7;
        float creg = c0[cb * HD + j0 + cjl];
        const float bi  = bias[j0 + cjl];
        const float bf_ = bias[HD + j0 + cjl];
        const float bg  = bias[2 * HD + j0 + cjl];
        const float bo_ = bias[3 * HD + j0 + cjl];

        const int kq0 = w >> 5, ks0 = (w >> 2) & 7, hi0 = w & 3;
        const int ust = ((kq0 * 8 + ks0) * 2 + (cb >> 4)) * 64 + hi0 * 16 + (cb & 15);
        const int* fp = &flags[kq * 32 + (l & 31)];

        for (int t = 0; t < TD; ++t) {
            if (t > 0) {
                for (;;) {
                    int f = __hip_atomic_load(fp, __ATOMIC_RELAXED, __HIP_MEMORY_SCOPE_AGENT);
                    if (__all(f >= t)) break;
                    __builtin_amdgcn_s_sleep(1);
                }
            }
            const short* hrb = hb + (size_t)(t & 1) * (BD * HD);

            bf16x8 a0[8], a1[8];
            #pragma unroll
            for (int ks = 0; ks < 8; ks++) {
                const short* p0 = hrb + ((size_t)(((kq * 8 + ks) * 2 + 0) * 64 + l)) * 8;
                const short* p1 = hrb + ((size_t)(((kq * 8 + ks) * 2 + 1) * 64 + l)) * 8;
                asm volatile("global_load_dwordx4 %0, %1, off sc1"
                             : "=v"(a0[ks]) : "v"(p0) : "memory");
                asm volatile("global_load_dwordx4 %0, %1, off sc1"
                             : "=v"(a1[ks]) : "v"(p1) : "memory");
            }
            asm volatile("s_waitcnt vmcnt(0)" ::: "memory");
            __builtin_amdgcn_sched_barrier(0);

            f32x4 acc[2][2] = {};
            #pragma unroll
            for (int ks = 0; ks < 8; ks++) {
                acc[0][0] = __builtin_amdgcn_mfma_f32_16x16x32_bf16(a0[ks], wb0[ks], acc[0][0], 0, 0, 0);
                acc[0][1] = __builtin_amdgcn_mfma_f32_16x16x32_bf16(a0[ks], wb1[ks], acc[0][1], 0, 0, 0);
                acc[1][0] = __builtin_amdgcn_mfma_f32_16x16x32_bf16(a1[ks], wb0[ks], acc[1][0], 0, 0, 0);
                acc[1][1] = __builtin_amdgcn_mfma_f32_16x16x32_bf16(a1[ks], wb1[ks], acc[1][1], 0, 0, 0);
            }
            #pragma unroll
            for (int mf = 0; mf < 2; mf++)
                #pragma unroll
                for (int nf = 0; nf < 2; nf++)
                    #pragma unroll
                    for (int r = 0; r < 4; r++)
                        gl[kq][mf * 16 + hi * 4 + r][nf * 16 + lo] = acc[mf][nf][r];
            __syncthreads();

            float xi = gl[0][cb][cjl]      + gl[1][cb][cjl]      + gl[2][cb][cjl]      + gl[3][cb][cjl]      + bi;
            float xf = gl[0][cb][8 + cjl]  + gl[1][cb][8 + cjl]  + gl[2][cb][8 + cjl]  + gl[3][cb][8 + cjl]  + bf_;
            float xg = gl[0][cb][16 + cjl] + gl[1][cb][16 + cjl] + gl[2][cb][16 + cjl] + gl[3][cb][16 + cjl] + bg;
            float xo = gl[0][cb][24 + cjl] + gl[1][cb][24 + cjl] + gl[2][cb][24 + cjl] + gl[3][cb][24 + cjl] + bo_;
            float cn = fsigmoid(xf) * creg + fsigmoid(xi) * ftanh(xg);
            float hn = fsigmoid(xo) * ftanh(cn);
            creg = cn;
            short hv = f2bf(hn);
            {
                unsigned int hval = (unsigned short)hv;
                short* hm  = Hmat + ((size_t)t * BD + cb) * HD + j0 + cjl;   // t-major
                short* hwb = hb + (size_t)((t + 1) & 1) * (BD * HD) + (size_t)ust * 8 + cjl;
                asm volatile("global_store_short %0, %1, off sc1" :: "v"(hm),  "v"(hval) : "memory");
                asm volatile("global_store_short %0, %1, off sc1" :: "v"(hwb), "v"(hval) : "memory");
            }
            asm volatile("s_waitcnt vmcnt(0)" ::: "memory");   // LLC-visible
            __syncthreads();                                   // all 256 h stores drained

            if (tid == 0)
                __hip_atomic_store(&flags[w], t + 1, __ATOMIC_RELAXED, __HIP_MEMORY_SCOPE_AGENT);
        }
    } else {
        // ================= streaming GEMM worker role =================
        const int lane = tid & 63, wv = tid >> 6;
        const int lo = lane & 15, hi = lane >> 4;
        const int wm = wv >> 1, wn = wv & 1;

        // staging decode (bank bijection): A units 0..511, B units 512..1023
        const int u0 = tid, u1 = tid + 256;
        const int r0 = (u0 >> 3) * 2 + (u0 & 1);
        const int r1 = (u1 >> 3) * 2 + (u1 & 1);
        const int kc0 = (((u0 & 7) - (r0 & 7)) & 7) >> 1;
        const int kc1 = (((u1 & 7) - (r1 & 7)) & 7) >> 1;

        int unitA[4], unitB[4];
        #pragma unroll
        for (int mf = 0; mf < 4; mf++) {
            int row = wm * 64 + mf * 16 + lo;
            unitA[mf] = (row >> 1) * 8 + ((2 * hi + (row & 7)) & 7);
        }
        #pragma unroll
        for (int nf = 0; nf < 4; nf++) {
            int row = wn * 64 + nf * 16 + lo;
            unitB[nf] = 512 + (row >> 1) * 8 + ((2 * hi + (row & 7)) & 7);
        }

        for (;;) {
            if (tid == 0)
                tau_sh = __hip_atomic_fetch_add(queue, 1, __ATOMIC_RELAXED, __HIP_MEMORY_SCOPE_AGENT);
            __syncthreads();
            int tau = tau_sh;
            if (tau >= NTT) break;
            int m = tau / NTN, n = tau - m * NTN;

            {   // tile m ready when all 128 WGs passed step 4m+3
                const int tgt = m * 4 + 4;
                if (tid < 64) {
                    const int* f0 = &flags[tid];
                    const int* f1 = &flags[tid + 64];
                    for (;;) {
                        int a = __hip_atomic_load(f0, __ATOMIC_RELAXED, __HIP_MEMORY_SCOPE_AGENT);
                        int b = __hip_atomic_load(f1, __ATOMIC_RELAXED, __HIP_MEMORY_SCOPE_AGENT);
                        if (__all(a >= tgt && b >= tgt)) break;
                        __builtin_amdgcn_s_sleep(16);
                    }
                }
                __syncthreads();
            }

            const short* pA0 = Hmat + ((long)m * 128 + r0) * HD + kc0 * 8;
            const short* pA1 = Hmat + ((long)m * 128 + r1) * HD + kc1 * 8;
            const short* pB0 = Bw + ((long)n * 128 + r0) * HD + kc0 * 8;
            const short* pB1 = Bw + ((long)n * 128 + r1) * HD + kc1 * 8;

#define GSTAGE(koff, bb) do { \
    __builtin_amdgcn_global_load_lds((const __attribute__((address_space(1))) short*)(pA0 + (koff)), \
        (__attribute__((address_space(3))) short*)&lds[((bb) + u0) * 8], 16, 0, 0); \
    __builtin_amdgcn_global_load_lds((const __attribute__((address_space(1))) short*)(pA1 + (koff)), \
        (__attribute__((address_space(3))) short*)&lds[((bb) + u1) * 8], 16, 0, 0); \
    __builtin_amdgcn_global_load_lds((const __attribute__((address_space(1))) short*)(pB0 + (koff)), \
        (__attribute__((address_space(3))) short*)&lds[((bb) + 512 + u0) * 8], 16, 0, 0); \
    __builtin_amdgcn_global_load_lds((const __attribute__((address_space(1))) short*)(pB1 + (koff)), \
        (__attribute__((address_space(3))) short*)&lds[((bb) + 512 + u1) * 8], 16, 0, 0); \
} while (0)

            f32x4 acc[4][4] = {};
            GSTAGE(0, 0);
            GSTAGE(32, 1024);
            asm volatile("s_waitcnt vmcnt(4)\n\ts_barrier" ::: "memory");

            for (int kt = 0; kt < 32; ++kt) {
                const int bb = (kt & 1) * 1024;
                bf16x8 a[4], b[4];
                #pragma unroll
                for (int mf = 0; mf < 4; mf++) a[mf] = *(const bf16x8*)&lds[(bb + unitA[mf]) * 8];
                #pragma unroll
                for (int nf = 0; nf < 4; nf++) b[nf] = *(const bf16x8*)&lds[(bb + unitB[nf]) * 8];
                __builtin_amdgcn_s_setprio(1);
                #pragma unroll
                for (int mf = 0; mf < 4; mf++)
                    #pragma unroll
                    for (int nf = 0; nf < 4; nf++)
                        acc[mf][nf] = __builtin_amdgcn_mfma_f32_16x16x32_bf16(a[mf], b[nf], acc[mf][nf], 0, 0, 0);
                __builtin_amdgcn_s_setprio(0);
                __builtin_amdgcn_s_barrier();          // all waves done reading bb
                if (kt + 2 < 32) {
                    GSTAGE((kt + 2) * 32, bb);
                    asm volatile("s_waitcnt vmcnt(4)" ::: "memory");
                } else {
                    asm volatile("s_waitcnt vmcnt(0)" ::: "memory");
                }
                __builtin_amdgcn_s_barrier();
            }
#undef GSTAGE

            // epilogue: C store + per-row sum(exp) -> rowsum_sh -> global
            if (tid < 128) rowsum_sh[tid] = 0.f;
            __syncthreads();
            float bo[4];
            #pragma unroll
            for (int nf = 0; nf < 4; nf++) bo[nf] = bout[n * 128 + wn * 64 + nf * 16 + lo];
            #pragma unroll
            for (int mf = 0; mf < 4; mf++)
                #pragma unroll
                for (int r = 0; r < 4; r++) {
                    int rloc = wm * 64 + mf * 16 + hi * 4 + r;
                    int trow = m * 128 + rloc;
                    int bt = trow & 31, tt = trow >> 5;
                    float* cp = C + ((long)bt * TD + tt) * VD + n * 128 + wn * 64 + lo;
                    float es = 0.f;
                    #pragma unroll
                    for (int nf = 0; nf < 4; nf++) {
                        float v = acc[mf][nf][r] + bo[nf];
                        cp[nf * 16] = v;
                        es += __expf(v);
                    }
                    es += __shfl_xor(es, 1, 64);
                    es += __shfl_xor(es, 2, 64);
                    es += __shfl_xor(es, 4, 64);
                    es += __shfl_xor(es, 8, 64);
                    if (lo == 0) atomicAdd(&rowsum_sh[rloc], es);
                }
            __syncthreads();
            if (tid < 128) {
                int trow = m * 128 + tid;
                int bt = trow & 31, tt = trow >> 5;
                float* rp = rowsum + bt * TD + tt;
                float val = rowsum_sh[tid];
                asm volatile("global_atomic_add_f32 %0, %1, off" :: "v"(rp), "v"(val) : "memory");
            }
            asm volatile("s_waitcnt vmcnt(0)" ::: "memory");
            __syncthreads();   // protect tau_sh + lds + rowsum_sh for next tile
        }
    }
}

// ---------------- final pass: x -= log(rowsum[row]) (in-place) ----------------
__global__ __launch_bounds__(256) void logsub(float* __restrict__ C,
                                              const float* __restrict__ rowsum)
{
    const long row = blockIdx.x;
    float* p = C + row * (long)VD;
    const float lse = logf(rowsum[row]);
    for (int i = threadIdx.x; i < VD / 4; i += 256) {
        float4 x = ((const float4*)p)[i];
        x.x -= lse; x.y -= lse; x.z -= lse; x.w -= lse;
        ((float4*)p)[i] = x;
    }
}

extern "C" void kernel_launch(void* const* d_in, const int* in_sizes, int n_in,
                              void* d_out, int out_size, void* d_ws, size_t ws_size,
                              hipStream_t stream)
{
    const float* h0   = (const float*)d_in[0];
    const float* c0   = (const float*)d_in[1];
    // d_in[2] = W_ih: decoder input is zeros, contributes only via b_ih.
    const float* Whh  = (const float*)d_in[3];
    const float* bih  = (const float*)d_in[4];
    const float* bhh  = (const float*)d_in[5];
    const float* Wout = (const float*)d_in[6];
    const float* bout = (const float*)d_in[7];

    char* ws = (char*)d_ws;
    short* Wout_b = (short*)ws;  ws += (size_t)VD * HD * 2;
    short* Whh_b  = (short*)ws;  ws += (size_t)4 * HD * HD * 2;
    short* Hmat   = (short*)ws;  ws += (size_t)BD * TD * HD * 2;  // t-major
    short* hb     = (short*)ws;  ws += (size_t)2 * BD * HD * 2;   // ping-pong h (fragment layout)
    float* bias   = (float*)ws;  ws += (size_t)4 * HD * 4;
    int*   ctr    = (int*)ws;    ws += 256 * sizeof(int);
    float* rowsum = (float*)ws;  ws += (size_t)BD * TD * 4;
    float* C      = (float*)d_out;

    int* flags = ctr;          // [128]
    int* queue = ctr + 128;    // [1]

    init_kernel<<<2048, 256, 0, stream>>>(Whh, bih, bhh, Wout, h0,
                                          Whh_b, Wout_b, bias, hb, ctr, rowsum);
    fused_lstm_gemm<<<NWG + GW, 256, 0, stream>>>(Whh_b, bias, c0, hb, Hmat,
                                                  Wout_b, bout, C, rowsum,
                                                  flags, queue);
    logsub<<<2048, 256, 0, stream>>>(C, rowsum);
}

// Round 14
// 479.460 us; speedup vs baseline: 1.2690x; 1.2690x over previous
//
#include <hip/hip_runtime.h>
#include <hip/hip_bf16.h>
#include <math.h>

#define HD 1024
#define BD 32
#define TD 64
#define VD 32000
#define NWG 128   // recurrence blocks (dispatched first, co-resident)
#define GW  512   // persistent GEMM worker blocks (queue-fed, any residency ok)
#define NTM 16    // 2048/128 M-tiles (t-major)
#define NTN 250   // 32000/128 N-tiles
#define NTT (NTM * NTN)

typedef __attribute__((ext_vector_type(8))) short bf16x8;
typedef __attribute__((ext_vector_type(4))) float f32x4;

__device__ __forceinline__ short f2bf(float x) {
    __hip_bfloat16 h = __float2bfloat16(x);
    union { __hip_bfloat16 h; short s; } u; u.h = h; return u.s;
}
__device__ __forceinline__ float fsigmoid(float x) {
    return 1.f / (1.f + __expf(-x));
}
__device__ __forceinline__ float ftanh(float x) {
    return 1.f - 2.f / (__expf(2.f * x) + 1.f);
}

// h ping-pong buffers live in MFMA-A-fragment order (same for all WGs):
// element (b, j): kq=j>>8, ks=(j>>5)&7, hi=(j>>3)&3, e=j&7, f=b>>4, lo=b&15
// 16B unit u = ((kq*8+ks)*2+f)*64 + hi*16 + lo ; short addr = u*8 + e.

// ---------------- init: casts + bias fold + state init ----------------
__global__ __launch_bounds__(256) void init_kernel(
    const float* __restrict__ Whh_f, const float* __restrict__ bih,
    const float* __restrict__ bhh,  const float* __restrict__ Wout_f,
    const float* __restrict__ h0,
    short* __restrict__ Whh_b, short* __restrict__ Wout_b,
    float* __restrict__ bias,  short* __restrict__ hb, int* __restrict__ ctr,
    float* __restrict__ rowsum)
{
    long i0 = (long)blockIdx.x * blockDim.x + threadIdx.x;
    long stride = (long)gridDim.x * blockDim.x;
    for (long i = i0; i < 21 * TD; i += stride) ctr[i] = 0;
    for (long i = i0; i < BD * TD; i += stride) rowsum[i] = 0.f;
    for (long i = i0; i < (long)VD * HD / 4; i += stride) {
        float4 x = ((const float4*)Wout_f)[i];
        short4 y; y.x = f2bf(x.x); y.y = f2bf(x.y); y.z = f2bf(x.z); y.w = f2bf(x.w);
        ((short4*)Wout_b)[i] = y;
    }
    for (long i = i0; i < (long)4 * HD * HD / 4; i += stride) {
        float4 x = ((const float4*)Whh_f)[i];
        short4 y; y.x = f2bf(x.x); y.y = f2bf(x.y); y.z = f2bf(x.z); y.w = f2bf(x.w);
        ((short4*)Whh_b)[i] = y;
    }
    for (long i = i0; i < 4 * HD; i += stride) bias[i] = bih[i] + bhh[i];
    for (long i = i0; i < BD * HD; i += stride) {   // ping buffer 0, fragment layout
        int b = (int)(i >> 10), j = (int)(i & 1023);
        int kq = j >> 8, ks = (j >> 5) & 7, hi = (j >> 3) & 3, e = j & 7;
        int u = ((kq * 8 + ks) * 2 + (b >> 4)) * 64 + hi * 16 + (b & 15);
        hb[u * 8 + e] = f2bf(h0[i]);
    }
}

// ---------------- fused: persistent LSTM (blocks 0..127) ---------------------
// ---------------- + queue-fed streaming logits GEMM (blocks 128..639) --------
// Recurrence + sync verbatim from R9 (measured fused=338us): ctrS->ctrQ tree,
// SINGLE-LANE polls (R13 lesson: multi-lane flag polling storms the LLC).
// Worker = R9 128^2 tile / 2-buffer ring + R10's proven rowsum epilogue.
__global__ __launch_bounds__(256, 2) void fused_lstm_gemm(
    const short* __restrict__ Whh_b,   // [4096][1024] bf16
    const float* __restrict__ bias,    // [4096]
    const float* __restrict__ c0,      // [32][1024] f32
    short* __restrict__ hb,            // [2][4096 units] bf16 fragment layout
    short* __restrict__ Hmat,          // [64*32][1024] bf16, t-major
    const short* __restrict__ Bw,      // W_out [32000][1024] bf16
    const float* __restrict__ bout,    // [32000]
    float* __restrict__ C,             // [2048][32000] b-major rows
    float* __restrict__ rowsum,        // [2048] sum(exp) per output row
    int* __restrict__ ctrS,            // [16][64] sub-arrival counters
    int* __restrict__ ctrQ,            // [4][64] quarter masters
    int* __restrict__ queue)           // [1] gemm tile queue
{
    __shared__ alignas(16) char shmem[32768];
    __shared__ float rowsum_sh[128];
    __shared__ int tau_sh;
    const int tid = threadIdx.x;

    if (blockIdx.x < NWG) {
        // ================= recurrence role =================
        __builtin_amdgcn_s_setprio(2);
        float (*gl)[32][36] = (float (*)[32][36])shmem;   // [kq][batch][col]
        const int w = blockIdx.x;
        const int kq = tid >> 6;
        const int l = tid & 63;
        const int lo = l & 15, hi = l >> 4;
        const int j0 = w * 8;
        const int kbase = kq * 256 + hi * 8;

        const short* wB0 = Whh_b + (long)((lo >> 3) * HD + j0 + (lo & 7)) * HD + kbase;
        const short* wB1 = Whh_b + (long)(((16 + lo) >> 3) * HD + j0 + ((16 + lo) & 7)) * HD + kbase;
        bf16x8 wb0[8], wb1[8];
        #pragma unroll
        for (int ks = 0; ks < 8; ks++) {
            wb0[ks] = *(const bf16x8*)(wB0 + ks * 32);
            wb1[ks] = *(const bf16x8*)(wB1 + ks * 32);
        }

        const int cb = tid >> 3, cjl = tid & 7;
        float creg = c0[cb * HD + j0 + cjl];
        const float bi  = bias[j0 + cjl];
        const float bf_ = bias[HD + j0 + cjl];
        const float bg  = bias[2 * HD + j0 + cjl];
        const float bo_ = bias[3 * HD + j0 + cjl];

        const int kq0 = w >> 5, ks0 = (w >> 2) & 7, hi0 = w & 3;
        const int sg = (w >> 3) & 3;
        const int ust = ((kq0 * 8 + ks0) * 2 + (cb >> 4)) * 64 + hi0 * 16 + (cb & 15);

        for (int t = 0; t < TD; ++t) {
            if (t > 0) {
                if (tid == 0) {   // single-lane poll of own quarter master
                    const int* cq = &ctrQ[kq0 * 0 + kq * TD + (t - 1)];
                    while (__hip_atomic_load(cq, __ATOMIC_RELAXED, __HIP_MEMORY_SCOPE_AGENT) < 4)
                        __builtin_amdgcn_s_sleep(1);
                }
                // note: each WAVE needs its own quarter; poll per-wave lane 0
                if ((l == 0) && tid != 0) {
                    const int* cq = &ctrQ[kq * TD + (t - 1)];
                    while (__hip_atomic_load(cq, __ATOMIC_RELAXED, __HIP_MEMORY_SCOPE_AGENT) < 4)
                        __builtin_amdgcn_s_sleep(1);
                }
                // wave-local: all lanes wait on lane 0's result via wave sync
                __builtin_amdgcn_wave_barrier();
            }
            // re-check with lane0 broadcast: lane 0 of each wave verified its
            // quarter; other lanes proceed (wave executes in lockstep after
            // the scalar branch above).
            const short* hrb = hb + (size_t)(t & 1) * (BD * HD);

            bf16x8 a0[8], a1[8];
            #pragma unroll
            for (int ks = 0; ks < 8; ks++) {
                const short* p0 = hrb + ((size_t)(((kq * 8 + ks) * 2 + 0) * 64 + l)) * 8;
                const short* p1 = hrb + ((size_t)(((kq * 8 + ks) * 2 + 1) * 64 + l)) * 8;
                asm volatile("global_load_dwordx4 %0, %1, off sc1"
                             : "=v"(a0[ks]) : "v"(p0) : "memory");
                asm volatile("global_load_dwordx4 %0, %1, off sc1"
                             : "=v"(a1[ks]) : "v"(p1) : "memory");
            }
            asm volatile("s_waitcnt vmcnt(0)" ::: "memory");
            __builtin_amdgcn_sched_barrier(0);

            f32x4 acc[2][2] = {};
            #pragma unroll
            for (int ks = 0; ks < 8; ks++) {
                acc[0][0] = __builtin_amdgcn_mfma_f32_16x16x32_bf16(a0[ks], wb0[ks], acc[0][0], 0, 0, 0);
                acc[0][1] = __builtin_amdgcn_mfma_f32_16x16x32_bf16(a0[ks], wb1[ks], acc[0][1], 0, 0, 0);
                acc[1][0] = __builtin_amdgcn_mfma_f32_16x16x32_bf16(a1[ks], wb0[ks], acc[1][0], 0, 0, 0);
                acc[1][1] = __builtin_amdgcn_mfma_f32_16x16x32_bf16(a1[ks], wb1[ks], acc[1][1], 0, 0, 0);
            }
            #pragma unroll
            for (int mf = 0; mf < 2; mf++)
                #pragma unroll
                for (int nf = 0; nf < 2; nf++)
                    #pragma unroll
                    for (int r = 0; r < 4; r++)
                        gl[kq][mf * 16 + hi * 4 + r][nf * 16 + lo] = acc[mf][nf][r];
            __syncthreads();

            float xi = gl[0][cb][cjl]      + gl[1][cb][cjl]      + gl[2][cb][cjl]      + gl[3][cb][cjl]      + bi;
            float xf = gl[0][cb][8 + cjl]  + gl[1][cb][8 + cjl]  + gl[2][cb][8 + cjl]  + gl[3][cb][8 + cjl]  + bf_;
            float xg = gl[0][cb][16 + cjl] + gl[1][cb][16 + cjl] + gl[2][cb][16 + cjl] + gl[3][cb][16 + cjl] + bg;
            float xo = gl[0][cb][24 + cjl] + gl[1][cb][24 + cjl] + gl[2][cb][24 + cjl] + gl[3][cb][24 + cjl] + bo_;
            float cn = fsigmoid(xf) * creg + fsigmoid(xi) * ftanh(xg);
            float hn = fsigmoid(xo) * ftanh(cn);
            creg = cn;
            short hv = f2bf(hn);
            {
                unsigned int hval = (unsigned short)hv;
                short* hm  = Hmat + ((size_t)t * BD + cb) * HD + j0 + cjl;   // t-major
                short* hwb = hb + (size_t)((t + 1) & 1) * (BD * HD) + (size_t)ust * 8 + cjl;
                asm volatile("global_store_short %0, %1, off sc1" :: "v"(hm),  "v"(hval) : "memory");
                asm volatile("global_store_short %0, %1, off sc1" :: "v"(hwb), "v"(hval) : "memory");
            }
            asm volatile("s_waitcnt vmcnt(0)" ::: "memory");   // LLC-visible
            __syncthreads();

            if (tid == 0) {   // arrival posted for ALL t (workers wait on t=63 too)
                int old = __hip_atomic_fetch_add(&ctrS[(kq0 * 4 + sg) * TD + t], 1,
                                                 __ATOMIC_RELAXED, __HIP_MEMORY_SCOPE_AGENT);
                if (old == 7)
                    __hip_atomic_fetch_add(&ctrQ[kq0 * TD + t], 1,
                                           __ATOMIC_RELAXED, __HIP_MEMORY_SCOPE_AGENT);
            }
        }
    } else {
        // ================= streaming GEMM worker role =================
        short* lds = (short*)shmem;     // 2 bufs x (A 512 + B 512 units) x 16B
        const int lane = tid & 63, wv = tid >> 6;
        const int lo = lane & 15, hi = lane >> 4;
        const int wm = wv >> 1, wn = wv & 1;

        // staging decode (bank bijection): u in [0,512)
        const int u0 = tid, u1 = tid + 256;
        const int r0 = (u0 >> 3) * 2 + (u0 & 1);
        const int r1 = (u1 >> 3) * 2 + (u1 & 1);
        const int kc0 = (((u0 & 7) - (r0 & 7)) & 7) >> 1;
        const int kc1 = (((u1 & 7) - (r1 & 7)) & 7) >> 1;

        int unitA[4], unitB[4];
        #pragma unroll
        for (int mf = 0; mf < 4; mf++) {
            int row = wm * 64 + mf * 16 + lo;
            unitA[mf] = (row >> 1) * 8 + ((2 * hi + (row & 7)) & 7);
        }
        #pragma unroll
        for (int nf = 0; nf < 4; nf++) {
            int row = wn * 64 + nf * 16 + lo;
            unitB[nf] = 512 + (row >> 1) * 8 + ((2 * hi + (row & 7)) & 7);
        }

        for (;;) {
            if (tid == 0)
                tau_sh = __hip_atomic_fetch_add(queue, 1, __ATOMIC_RELAXED, __HIP_MEMORY_SCOPE_AGENT);
            __syncthreads();
            int tau = tau_sh;
            if (tau >= NTT) break;
            int m = tau / NTN, n = tau - m * NTN;

            if (tid == 0) {   // tile m ready after step m*4+3 by all 4 quarters
                int tr = m * 4 + 3;
                #pragma unroll
                for (int q = 0; q < 4; q++)
                    while (__hip_atomic_load(&ctrQ[q * TD + tr], __ATOMIC_RELAXED,
                                             __HIP_MEMORY_SCOPE_AGENT) < 4)
                        __builtin_amdgcn_s_sleep(8);
            }
            __syncthreads();

            const short* pA0 = Hmat + ((long)m * 128 + r0) * HD + kc0 * 8;
            const short* pA1 = Hmat + ((long)m * 128 + r1) * HD + kc1 * 8;
            const short* pB0 = Bw + ((long)n * 128 + r0) * HD + kc0 * 8;
            const short* pB1 = Bw + ((long)n * 128 + r1) * HD + kc1 * 8;

#define GSTAGE(koff, bb) do { \
    __builtin_amdgcn_global_load_lds((const __attribute__((address_space(1))) short*)(pA0 + (koff)), \
        (__attribute__((address_space(3))) short*)&lds[((bb) + u0) * 8], 16, 0, 0); \
    __builtin_amdgcn_global_load_lds((const __attribute__((address_space(1))) short*)(pA1 + (koff)), \
        (__attribute__((address_space(3))) short*)&lds[((bb) + u1) * 8], 16, 0, 0); \
    __builtin_amdgcn_global_load_lds((const __attribute__((address_space(1))) short*)(pB0 + (koff)), \
        (__attribute__((address_space(3))) short*)&lds[((bb) + 512 + u0) * 8], 16, 0, 0); \
    __builtin_amdgcn_global_load_lds((const __attribute__((address_space(1))) short*)(pB1 + (koff)), \
        (__attribute__((address_space(3))) short*)&lds[((bb) + 512 + u1) * 8], 16, 0, 0); \
} while (0)

            f32x4 acc[4][4] = {};
            GSTAGE(0, 0);
            GSTAGE(32, 1024);
            asm volatile("s_waitcnt vmcnt(4)\n\ts_barrier" ::: "memory");

            for (int kt = 0; kt < 32; ++kt) {
                const int bb = (kt & 1) * 1024;
                bf16x8 a[4], b[4];
                #pragma unroll
                for (int mf = 0; mf < 4; mf++) a[mf] = *(const bf16x8*)&lds[(bb + unitA[mf]) * 8];
                #pragma unroll
                for (int nf = 0; nf < 4; nf++) b[nf] = *(const bf16x8*)&lds[(bb + unitB[nf]) * 8];
                __builtin_amdgcn_s_setprio(1);
                #pragma unroll
                for (int mf = 0; mf < 4; mf++)
                    #pragma unroll
                    for (int nf = 0; nf < 4; nf++)
                        acc[mf][nf] = __builtin_amdgcn_mfma_f32_16x16x32_bf16(a[mf], b[nf], acc[mf][nf], 0, 0, 0);
                __builtin_amdgcn_s_setprio(0);
                __builtin_amdgcn_s_barrier();          // all waves done reading bb
                if (kt + 2 < 32) {
                    GSTAGE((kt + 2) * 32, bb);
                    asm volatile("s_waitcnt vmcnt(4)" ::: "memory");
                } else {
                    asm volatile("s_waitcnt vmcnt(0)" ::: "memory");
                }
                __builtin_amdgcn_s_barrier();
            }
#undef GSTAGE

            // epilogue: C store + per-row sum(exp) -> rowsum_sh -> global (R10)
            if (tid < 128) rowsum_sh[tid] = 0.f;
            __syncthreads();
            float bo[4];
            #pragma unroll
            for (int nf = 0; nf < 4; nf++) bo[nf] = bout[n * 128 + wn * 64 + nf * 16 + lo];
            #pragma unroll
            for (int mf = 0; mf < 4; mf++)
                #pragma unroll
                for (int r = 0; r < 4; r++) {
                    int rloc = wm * 64 + mf * 16 + hi * 4 + r;
                    int trow = m * 128 + rloc;
                    int bt = trow & 31, tt = trow >> 5;
                    float* cp = C + ((long)bt * TD + tt) * VD + n * 128 + wn * 64 + lo;
                    float es = 0.f;
                    #pragma unroll
                    for (int nf = 0; nf < 4; nf++) {
                        float v = acc[mf][nf][r] + bo[nf];
                        cp[nf * 16] = v;
                        es += __expf(v);
                    }
                    es += __shfl_xor(es, 1, 64);
                    es += __shfl_xor(es, 2, 64);
                    es += __shfl_xor(es, 4, 64);
                    es += __shfl_xor(es, 8, 64);
                    if (lo == 0) atomicAdd(&rowsum_sh[rloc], es);
                }
            __syncthreads();
            if (tid < 128) {
                int trow = m * 128 + tid;
                int bt = trow & 31, tt = trow >> 5;
                float* rp = rowsum + bt * TD + tt;
                float val = rowsum_sh[tid];
                asm volatile("global_atomic_add_f32 %0, %1, off" :: "v"(rp), "v"(val) : "memory");
            }
            asm volatile("s_waitcnt vmcnt(0)" ::: "memory");
            __syncthreads();   // protect tau_sh + lds + rowsum_sh for next tile
        }
    }
}

// ---------------- final pass: x -= log(rowsum[row]) (in-place) ----------------
__global__ __launch_bounds__(256) void logsub(float* __restrict__ C,
                                              const float* __restrict__ rowsum)
{
    const long row = blockIdx.x;
    float* p = C + row * (long)VD;
    const float lse = logf(rowsum[row]);
    for (int i = threadIdx.x; i < VD / 4; i += 256) {
        float4 x = ((const float4*)p)[i];
        x.x -= lse; x.y -= lse; x.z -= lse; x.w -= lse;
        ((float4*)p)[i] = x;
    }
}

extern "C" void kernel_launch(void* const* d_in, const int* in_sizes, int n_in,
                              void* d_out, int out_size, void* d_ws, size_t ws_size,
                              hipStream_t stream)
{
    const float* h0   = (const float*)d_in[0];
    const float* c0   = (const float*)d_in[1];
    // d_in[2] = W_ih: decoder input is zeros, contributes only via b_ih.
    const float* Whh  = (const float*)d_in[3];
    const float* bih  = (const float*)d_in[4];
    const float* bhh  = (const float*)d_in[5];
    const float* Wout = (const float*)d_in[6];
    const float* bout = (const float*)d_in[7];

    char* ws = (char*)d_ws;
    short* Wout_b = (short*)ws;  ws += (size_t)VD * HD * 2;
    short* Whh_b  = (short*)ws;  ws += (size_t)4 * HD * HD * 2;
    short* Hmat   = (short*)ws;  ws += (size_t)BD * TD * HD * 2;  // t-major
    short* hb     = (short*)ws;  ws += (size_t)2 * BD * HD * 2;   // ping-pong h (fragment layout)
    float* bias   = (float*)ws;  ws += (size_t)4 * HD * 4;
    int*   ctr    = (int*)ws;    ws += 21 * TD * sizeof(int);
    float* rowsum = (float*)ws;  ws += (size_t)BD * TD * 4;
    float* C      = (float*)d_out;

    int* ctrS  = ctr;             // [16][64]
    int* ctrQ  = ctr + 16 * TD;   // [4][64]
    int* queue = ctr + 20 * TD;   // [1]

    init_kernel<<<2048, 256, 0, stream>>>(Whh, bih, bhh, Wout, h0,
                                          Whh_b, Wout_b, bias, hb, ctr, rowsum);
    fused_lstm_gemm<<<NWG + GW, 256, 0, stream>>>(Whh_b, bias, c0, hb, Hmat,
                                                  Wout_b, bout, C, rowsum,
                                                  ctrS, ctrQ, queue);
    logsub<<<2048, 256, 0, stream>>>(C, rowsum);
}